// Round 6
// baseline (12052.881 us; speedup 1.0000x reference)
//
#include <hip/hip_runtime.h>
#include <math.h>

// NTM, batch-parallel: batches are fully independent through the recurrence,
// so block b owns batch n=b end-to-end: 64 steps, NO grid barriers, NO
// cross-block traffic. Per-step state (h,k,r,w) in LDS; weights stream from
// L2/LLC (shared read-only by 4 blocks/XCD); c_x read once/step from HBM
// (second pass L2-hits). cscan kernel streams the 268 MB cs output.
// Shapes: N=32, T=64, C1=128, C2=256, H=512 (all f32).

#define NBAT 32
#define TSTEPS 64
#define C1D 128
#define C2D 256
#define HD 512
#define TPB 1024
#define LN2F 0.6931471805599453f

typedef float f32x4 __attribute__((ext_vector_type(4)));

static __device__ __forceinline__ float dot4f(float4 a, float4 b) {
  return a.x * b.x + a.y * b.y + a.z * b.z + a.w * b.w;
}
static __device__ __forceinline__ float sigm(float x) { return 1.0f / (1.0f + __expf(-x)); }

__global__ void __launch_bounds__(TPB) ntm_chain(
    const float* __restrict__ h0, const float* __restrict__ c_x,
    const float* __restrict__ Wk, const float* __restrict__ bk,
    const float* __restrict__ Wb, const float* __restrict__ bb,
    const float* __restrict__ We, const float* __restrict__ be,
    const float* __restrict__ Wv, const float* __restrict__ bv,
    const float* __restrict__ Wih, const float* __restrict__ bih,
    const float* __restrict__ Whh, const float* __restrict__ bhh,
    float* __restrict__ hs_out, float* __restrict__ wsf)
{
  const int tid = threadIdx.x;
  const int n = blockIdx.x;  // batch

  float* wbuf = wsf;                           // [N*T*C1] final softmax weights
  float* earr = wbuf + NBAT * TSTEPS * C1D;    // [N*T*C2]
  float* varr = earr + NBAT * TSTEPS * C2D;    // [N*T*C2]

  __shared__ float s_h[2][HD];    // ping-pong h state
  __shared__ float s_k[C2D];
  __shared__ float s_r[C2D];
  __shared__ float s_rp[4][C2D];  // r partials
  __shared__ float s_w[C1D];      // softmax weights
  __shared__ float s_sc[C1D];     // raw scores
  __shared__ float s_misc[8];     // [0]=||k||, [1]=beta

  if (tid < HD) s_h[0][tid] = h0[n * HD + tid];
  __syncthreads();

  int cur = 0;

  // PROJ: k,beta (for next attention) and e,v (for cscan) from s_h[cur].
  auto proj = [&](int t, bool write_ev) {
    const int ch = tid >> 2, s4 = tid & 3;
    const float* hp = s_h[cur] + s4 * 128;
    const float* wkp = Wk + (size_t)ch * HD + s4 * 128;
    const float* wep = We + (size_t)ch * HD + s4 * 128;
    const float* wvp = Wv + (size_t)ch * HD + s4 * 128;
    float ka = 0, ea = 0, va = 0;
#pragma unroll 8
    for (int x = 0; x < 32; ++x) {
      const float4 hv = *(const float4*)(hp + x * 4);
      ka += dot4f(hv, *(const float4*)(wkp + x * 4));
      if (write_ev) {
        ea += dot4f(hv, *(const float4*)(wep + x * 4));
        va += dot4f(hv, *(const float4*)(wvp + x * 4));
      }
    }
    ka += __shfl_xor(ka, 1); ka += __shfl_xor(ka, 2);
    if (write_ev) {
      ea += __shfl_xor(ea, 1); ea += __shfl_xor(ea, 2);
      va += __shfl_xor(va, 1); va += __shfl_xor(va, 2);
    }
    if (s4 == 0) {
      s_k[ch] = ka + bk[ch];
      if (write_ev) {
        earr[(size_t)(n * TSTEPS + t) * C2D + ch] = sigm(ea + be[ch]);
        varr[(size_t)(n * TSTEPS + t) * C2D + ch] = va + bv[ch];
      }
    }
    if (tid < 4) {  // beta (ch-0 quad does double duty; negligible straggle)
      const float* wbp = Wb + tid * 128;
      const float* hp2 = s_h[cur] + tid * 128;
      float ba = 0;
#pragma unroll 8
      for (int x = 0; x < 32; ++x)
        ba += dot4f(*(const float4*)(hp2 + x * 4), *(const float4*)(wbp + x * 4));
      ba += __shfl_xor(ba, 1); ba += __shfl_xor(ba, 2);
      if (tid == 0) {
        const float xb = ba + bb[0];
        const float bpos = fmaxf(xb, 0.f), bneg = fminf(xb, 0.f);
        s_misc[1] = log1pf(__expf(bneg)) + bpos + log1pf(__expf(-bpos)) + (1.0f - LN2F);
      }
    }
  };

  auto knorm = [&]() {
    if (tid < 64) {
      float sq = 0;
#pragma unroll
      for (int x = 0; x < 4; ++x) { const float v = s_k[tid + 64 * x]; sq += v * v; }
#pragma unroll
      for (int m = 1; m < 64; m <<= 1) sq += __shfl_xor(sq, m);
      if (tid == 0) s_misc[0] = sqrtf(sq);
    }
  };

  proj(-1, false);
  __syncthreads();
  knorm();
  __syncthreads();

  for (int t = 0; t < TSTEPS; ++t) {
    const float* cxt = c_x + (size_t)(n * TSTEPS + t) * C1D * C2D;

    // ---- P2: scores (8 threads per i-row; c_x first read, HBM) ----
    {
      const int row = tid >> 3, s8 = tid & 7;
      const float* xp = cxt + row * C2D + s8 * 32;
      const float* kp = s_k + s8 * 32;
      float np = 0, cp = 0;
#pragma unroll
      for (int x = 0; x < 8; ++x) {
        const float4 xv = *(const float4*)(xp + x * 4);
        np += dot4f(xv, *(const float4*)(kp + x * 4));
        cp += dot4f(xv, xv);
      }
      np += __shfl_xor(np, 1); cp += __shfl_xor(cp, 1);
      np += __shfl_xor(np, 2); cp += __shfl_xor(cp, 2);
      np += __shfl_xor(np, 4); cp += __shfl_xor(cp, 4);
      if (s8 == 0) {
        const float kn = s_misc[0], beta = s_misc[1];
        s_sc[row] = beta * np / fmaxf(sqrtf(cp) * kn, 1e-8f);
      }
    }
    __syncthreads();

    // ---- P3: softmax over 128 (wave 0) -> s_w + final w to global ----
    if (tid < 64) {
      const float a = s_sc[tid], b = s_sc[tid + 64];
      float mx = fmaxf(a, b);
#pragma unroll
      for (int m = 1; m < 64; m <<= 1) mx = fmaxf(mx, __shfl_xor(mx, m));
      const float p0 = __expf(a - mx), p1 = __expf(b - mx);
      float L = p0 + p1;
#pragma unroll
      for (int m = 1; m < 64; m <<= 1) L += __shfl_xor(L, m);
      const float iL = 1.f / L;
      const float w0 = p0 * iL, w1 = p1 * iL;
      s_w[tid] = w0; s_w[tid + 64] = w1;
      wbuf[(size_t)(n * TSTEPS + t) * C1D + tid] = w0;
      wbuf[(size_t)(n * TSTEPS + t) * C1D + tid + 64] = w1;
    }
    __syncthreads();

    // ---- P4: r = sum_i w_i * cx[i,:] (c_x second read, L2-hit) ----
    {
      const int c = tid & 255, g = tid >> 8;
      const float* xp = cxt + (g * 32) * C2D + c;
      float acc = 0;
#pragma unroll 8
      for (int i = 0; i < 32; ++i) acc += s_w[g * 32 + i] * xp[i * C2D];
      s_rp[g][c] = acc;
    }
    __syncthreads();
    if (tid < C2D)
      s_r[tid] = s_rp[0][tid] + s_rp[1][tid] + s_rp[2][tid] + s_rp[3][tid];
    __syncthreads();

    // ---- P5: GRU (2 threads per feature j; halves combined via shfl) ----
    {
      const int j = tid >> 1, hf = tid & 1;
      float aR = 0, aZ = 0, aNi = 0, aNh = 0;
      const float* rp = s_r + hf * 128;
      const float* hp = s_h[cur] + hf * 256;
      {
        const float* wi0 = Wih + (size_t)(0 * HD + j) * C2D + hf * 128;
        const float* wi1 = Wih + (size_t)(1 * HD + j) * C2D + hf * 128;
        const float* wi2 = Wih + (size_t)(2 * HD + j) * C2D + hf * 128;
#pragma unroll 8
        for (int x = 0; x < 32; ++x) {
          const float4 rv = *(const float4*)(rp + x * 4);
          aR  += dot4f(rv, *(const float4*)(wi0 + x * 4));
          aZ  += dot4f(rv, *(const float4*)(wi1 + x * 4));
          aNi += dot4f(rv, *(const float4*)(wi2 + x * 4));
        }
      }
      {
        const float* wh0 = Whh + (size_t)(0 * HD + j) * HD + hf * 256;
        const float* wh1 = Whh + (size_t)(1 * HD + j) * HD + hf * 256;
        const float* wh2 = Whh + (size_t)(2 * HD + j) * HD + hf * 256;
#pragma unroll 8
        for (int x = 0; x < 64; ++x) {
          const float4 hv = *(const float4*)(hp + x * 4);
          aR  += dot4f(hv, *(const float4*)(wh0 + x * 4));
          aZ  += dot4f(hv, *(const float4*)(wh1 + x * 4));
          aNh += dot4f(hv, *(const float4*)(wh2 + x * 4));
        }
      }
      aR += __shfl_xor(aR, 1);
      aZ += __shfl_xor(aZ, 1);
      aNi += __shfl_xor(aNi, 1);
      aNh += __shfl_xor(aNh, 1);
      if (hf == 0) {
        const float rg = sigm(aR + bih[j] + bhh[j]);
        const float z  = sigm(aZ + bih[HD + j] + bhh[HD + j]);
        const float ng = tanhf(aNi + bih[2 * HD + j] + rg * (aNh + bhh[2 * HD + j]));
        const float hn = (1.f - z) * ng + z * s_h[cur][j];
        s_h[cur ^ 1][j] = hn;
        hs_out[(size_t)(n * TSTEPS + t) * HD + j] = hn;
      }
    }
    __syncthreads();
    cur ^= 1;

    // ---- P6: e,v for step t + k,beta for step t+1 (from h_t) ----
    proj(t, true);
    __syncthreads();
    knorm();
    __syncthreads();
  }
}

// ---- parallel c-scan: c_t = c_{t-1}*(1 - w_t e_t) + w_t v_t ----
__global__ void __launch_bounds__(256) ntm_cscan(
    const float* __restrict__ c0, const float* __restrict__ wsf,
    float* __restrict__ out)
{
  const float* wbuf = wsf;
  const float* earr = wbuf + NBAT * TSTEPS * C1D;
  const float* varr = earr + NBAT * TSTEPS * C2D;
  float* cs_out = out + NBAT * TSTEPS * HD;

  const int tid = threadIdx.x;
  const int lane = tid & 63, wid = tid >> 6;
  const int n = blockIdx.x >> 3, g = blockIdx.x & 7;
  const int i0 = g * 16 + wid * 4;

  f32x4 c[4];
#pragma unroll
  for (int r = 0; r < 4; ++r)
    c[r] = *(const f32x4*)(c0 + ((size_t)(n * C1D + i0 + r)) * C2D + lane * 4);

  const float* ep = earr + (size_t)n * TSTEPS * C2D + lane * 4;
  const float* vp = varr + (size_t)n * TSTEPS * C2D + lane * 4;
  const float* wp = wbuf + (size_t)n * TSTEPS * C1D + i0;

  f32x4 e_nxt = *(const f32x4*)(ep);
  f32x4 v_nxt = *(const f32x4*)(vp);
  for (int t = 0; t < TSTEPS; ++t) {
    const f32x4 e4 = e_nxt, v4 = v_nxt;
    if (t + 1 < TSTEPS) {
      e_nxt = *(const f32x4*)(ep + (t + 1) * C2D);
      v_nxt = *(const f32x4*)(vp + (t + 1) * C2D);
    }
#pragma unroll
    for (int r = 0; r < 4; ++r) {
      const float wr = wp[t * C1D + r];
      c[r] = c[r] * (1.f - wr * e4) + wr * v4;
      __builtin_nontemporal_store(
          c[r], (f32x4*)(cs_out + ((size_t)((n * TSTEPS + t) * C1D + i0 + r)) * C2D + lane * 4));
    }
  }
}

extern "C" void kernel_launch(void* const* d_in, const int* in_sizes, int n_in,
                              void* d_out, int out_size, void* d_ws, size_t ws_size,
                              hipStream_t stream) {
  const float* h0 = (const float*)d_in[0];
  const float* c0 = (const float*)d_in[1];
  const float* c_x = (const float*)d_in[2];
  const float* Wk = (const float*)d_in[3];
  const float* bk = (const float*)d_in[4];
  const float* Wb = (const float*)d_in[5];
  const float* bb = (const float*)d_in[6];
  const float* We = (const float*)d_in[7];
  const float* be = (const float*)d_in[8];
  const float* Wv = (const float*)d_in[9];
  const float* bv = (const float*)d_in[10];
  const float* Wih = (const float*)d_in[11];
  const float* bih = (const float*)d_in[12];
  const float* Whh = (const float*)d_in[13];
  const float* bhh = (const float*)d_in[14];

  float* wsf = (float*)d_ws;

  ntm_chain<<<dim3(NBAT), dim3(TPB), 0, stream>>>(h0, c_x, Wk, bk, Wb, bb, We, be, Wv, bv,
                                                  Wih, bih, Whh, bhh, (float*)d_out, wsf);
  ntm_cscan<<<dim3(256), dim3(256), 0, stream>>>(c0, wsf, (float*)d_out);
}

// Round 7
// 3061.651 us; speedup vs baseline: 3.9367x; 3.9367x over previous
//
#include <hip/hip_runtime.h>
#include <math.h>

// NTM chain kernel: 128 blocks x 256 threads, 3 phases/step, all-poll flag barrier.
//  Phase A: blocks 0-31: full attention (softmax+r) for batch n=bid (c_x plain/cached);
//           blocks 32-95: e,v matvecs for step t-1 (off critical path).
//  Phase B: GRU, 4 h-features/block, weights LDS-resident (loaded once).
//  Phase C: k (2 ch/block) + beta for t+1.
// Cross-block state (r, h, k, beta) via agent-scope relaxed atomics, wide+contiguous
// (LLC-coherent, no L2 flush fences anywhere). Big streams (w, e, v, hs) are plain
// cached stores -> kernel-end writeback -> consumed by cscan kernel / host.
// cscan: parallel scan c_t = c_{t-1}(1 - w_t e_t) + w_t v_t, streams 268 MB.
// Shapes: N=32, T=64, C1=128, C2=256, H=512 (all f32).

#define NBAT 32
#define TSTEPS 64
#define C1D 128
#define C2D 256
#define HD 512
#define NBLK 128
#define LN2F 0.6931471805599453f

typedef float f32x4 __attribute__((ext_vector_type(4)));

static __device__ __forceinline__ float dot4f(float4 a, float4 b) {
  return a.x * b.x + a.y * b.y + a.z * b.z + a.w * b.w;
}
static __device__ __forceinline__ float sigm(float x) { return 1.0f / (1.0f + __expf(-x)); }

// ---- agent-scope (LLC-coherent, fence-free) helpers ----
static __device__ __forceinline__ float aload(const float* p) {
  return __hip_atomic_load(p, __ATOMIC_RELAXED, __HIP_MEMORY_SCOPE_AGENT);
}
static __device__ __forceinline__ void astore(float* p, float v) {
  __hip_atomic_store(p, v, __ATOMIC_RELAXED, __HIP_MEMORY_SCOPE_AGENT);
}
static __device__ __forceinline__ float2 aload2(const float* p) {
  unsigned long long u = __hip_atomic_load((const unsigned long long*)p,
                                           __ATOMIC_RELAXED, __HIP_MEMORY_SCOPE_AGENT);
  union { unsigned long long u; float2 f; } c;
  c.u = u;
  return c.f;
}
static __device__ __forceinline__ void astore2(float* p, float a, float b) {
  union { float f[2]; unsigned long long u; } c;
  c.f[0] = a; c.f[1] = b;
  __hip_atomic_store((unsigned long long*)p, c.u, __ATOMIC_RELAXED, __HIP_MEMORY_SCOPE_AGENT);
}
static __device__ __forceinline__ float4 aload4(const float* p) {
  const float2 lo = aload2(p), hi = aload2(p + 2);
  return make_float4(lo.x, lo.y, hi.x, hi.y);
}

__global__ void __launch_bounds__(256) ntm_chain(
    const float* __restrict__ h0, const float* __restrict__ c_x,
    const float* __restrict__ Wk, const float* __restrict__ bk,
    const float* __restrict__ Wb, const float* __restrict__ bb,
    const float* __restrict__ We, const float* __restrict__ be,
    const float* __restrict__ Wv, const float* __restrict__ bv,
    const float* __restrict__ Wih, const float* __restrict__ bih,
    const float* __restrict__ Whh, const float* __restrict__ bhh,
    float* __restrict__ hs_out, float* __restrict__ wsf, unsigned* __restrict__ flags)
{
  const int tid = threadIdx.x;
  const int bid = blockIdx.x;

  // ---- workspace (floats) ----
  float* hb0   = wsf;                      // [32*512]
  float* hb1   = hb0 + NBAT * HD;          // [32*512]
  float* kbuf  = hb1 + NBAT * HD;          // [32*256]
  float* betab = kbuf + NBAT * C2D;        // [32] (+pad)
  float* rbuf  = betab + 64;               // [32*256]
  float* wbuf  = rbuf + NBAT * C2D;        // [32*64*128] final softmax w (plain)
  float* earr  = wbuf + NBAT * TSTEPS * C1D;  // [32*64*256] (plain)
  float* varr  = earr + NBAT * TSTEPS * C2D;  // [32*64*256] (plain)

  // ---- LDS (~96 KB) ----
  __shared__ float s_k[C2D];
  __shared__ float s_sc[C1D];
  __shared__ float s_w[C1D];
  __shared__ float s_misc[8];       // [0]=||k||, [1]=beta
  __shared__ float s_r[NBAT * 264];
  __shared__ float s_wih[12 * 260];
  __shared__ float s_whh[12 * 516];
  __shared__ float s_wk[2 * 516];
  __shared__ float s_wev[8 * 516];  // rows 0-3: We, rows 4-7: Wv (blocks 32..95)
  __shared__ float s_wb[HD];

  const int j0 = bid * 4;          // GRU features
  const int kch = bid * 2;         // k channels
  const int evch = (bid - 32) * 4; // e/v channels (blocks 32..95)

  for (int idx = tid; idx < 12 * C2D; idx += 256) {
    const int row = idx >> 8, c = idx & (C2D - 1);
    const int f = row / 3, g = row % 3;
    s_wih[row * 260 + c] = Wih[(g * HD + j0 + f) * C2D + c];
  }
  for (int idx = tid; idx < 12 * HD; idx += 256) {
    const int row = idx >> 9, c = idx & (HD - 1);
    const int f = row / 3, g = row % 3;
    s_whh[row * 516 + c] = Whh[(g * HD + j0 + f) * HD + c];
  }
  for (int idx = tid; idx < 2 * HD; idx += 256) {
    const int row = idx >> 9, c = idx & (HD - 1);
    s_wk[row * 516 + c] = Wk[(kch + row) * HD + c];
  }
  if (bid >= 32 && bid < 96) {
    for (int idx = tid; idx < 8 * HD; idx += 256) {
      const int row = idx >> 9, c = idx & (HD - 1);
      const float* __restrict__ src = (row < 4) ? We : Wv;
      s_wev[row * 516 + c] = src[(evch + (row & 3)) * HD + c];
    }
  }
  for (int idx = tid; idx < HD; idx += 256) s_wb[idx] = Wb[idx];
  __syncthreads();

  unsigned gen = 0;
  // All-poll flag barrier: arrive = one relaxed agent store to own 128B line;
  // wave 0 of every block polls all 128 flags (2 per lane), no master hop.
  auto gridbar = [&]() {
    ++gen;
    asm volatile("s_waitcnt vmcnt(0) lgkmcnt(0)" ::: "memory");
    __syncthreads();
    if (tid == 0)
      __hip_atomic_store(flags + bid * 32, gen, __ATOMIC_RELAXED, __HIP_MEMORY_SCOPE_AGENT);
    if (tid < 64) {
      const unsigned* f0 = flags + (2 * tid) * 32;
      const unsigned* f1 = flags + (2 * tid + 1) * 32;
      while (true) {
        const unsigned a = __hip_atomic_load(f0, __ATOMIC_RELAXED, __HIP_MEMORY_SCOPE_AGENT);
        const unsigned b = __hip_atomic_load(f1, __ATOMIC_RELAXED, __HIP_MEMORY_SCOPE_AGENT);
        if (__all(a >= gen && b >= gen)) break;
        __builtin_amdgcn_s_sleep(2);
      }
    }
    __syncthreads();
  };

  // ---- Phase C: k (2 ch) for t+1; beta (block 0) ----
  auto proj_k = [&](const float* __restrict__ hsrc) {
    const int n = tid >> 3, s = tid & 7;
    const float* hp = hsrc + n * HD;
    float k0 = 0, k1 = 0, bp = 0;
#pragma unroll
    for (int x = 0; x < 16; ++x) {
      const int cix = s * 64 + ((4 * x + 8 * s) & 63);
      const float4 hv = aload4(hp + cix);
      k0 += dot4f(hv, *(const float4*)(s_wk + cix));
      k1 += dot4f(hv, *(const float4*)(s_wk + 516 + cix));
      if (bid == 0) bp += dot4f(hv, *(const float4*)(s_wb + cix));
    }
#pragma unroll
    for (int m = 1; m < 8; m <<= 1) { k0 += __shfl_xor(k0, m); k1 += __shfl_xor(k1, m); }
    if (bid == 0) {
#pragma unroll
      for (int m = 1; m < 8; m <<= 1) bp += __shfl_xor(bp, m);
    }
    if (s == 0) {
      astore2(kbuf + n * C2D + kch, k0 + bk[kch], k1 + bk[kch + 1]);
      if (bid == 0) {
        const float xb = bp + bb[0];
        const float bpos = fmaxf(xb, 0.f), bneg = fminf(xb, 0.f);
        astore(betab + n, log1pf(__expf(bneg)) + bpos + log1pf(__expf(-bpos)) + (1.0f - LN2F));
      }
    }
  };

  // ---- e,v for step te from hsrc (blocks 32..95, 4 channels each) ----
  auto phase_ev = [&](const float* __restrict__ hsrc, int te) {
    const int n = tid >> 3, s = tid & 7;
    const float* hp = hsrc + n * HD;
    float e[4] = {0, 0, 0, 0}, v[4] = {0, 0, 0, 0};
#pragma unroll
    for (int x = 0; x < 16; ++x) {
      const int cix = s * 64 + ((4 * x + 8 * s) & 63);
      const float4 hv = aload4(hp + cix);
#pragma unroll
      for (int f = 0; f < 4; ++f) {
        e[f] += dot4f(hv, *(const float4*)(s_wev + f * 516 + cix));
        v[f] += dot4f(hv, *(const float4*)(s_wev + (4 + f) * 516 + cix));
      }
    }
#pragma unroll
    for (int m = 1; m < 8; m <<= 1) {
#pragma unroll
      for (int f = 0; f < 4; ++f) { e[f] += __shfl_xor(e[f], m); v[f] += __shfl_xor(v[f], m); }
    }
    if (s == 0) {
      *(float4*)(earr + (size_t)(n * TSTEPS + te) * C2D + evch) =
          make_float4(sigm(e[0] + be[evch]), sigm(e[1] + be[evch + 1]),
                      sigm(e[2] + be[evch + 2]), sigm(e[3] + be[evch + 3]));
      *(float4*)(varr + (size_t)(n * TSTEPS + te) * C2D + evch) =
          make_float4(v[0] + bv[evch], v[1] + bv[evch + 1],
                      v[2] + bv[evch + 2], v[3] + bv[evch + 3]);
    }
  };

  // ---- Phase A attention: full softmax + r for batch n=bid (blocks 0..31) ----
  auto phase_attn = [&](int t) {
    const int n = bid;
    const float* cxt = c_x + (size_t)(n * TSTEPS + t) * C1D * C2D;
    if (tid < 64) {
      const float4 kv = aload4(kbuf + n * C2D + tid * 4);
      *(float4*)(s_k + tid * 4) = kv;
      float sq = kv.x * kv.x + kv.y * kv.y + kv.z * kv.z + kv.w * kv.w;
#pragma unroll
      for (int m = 1; m < 64; m <<= 1) sq += __shfl_xor(sq, m);
      if (tid == 0) s_misc[0] = sqrtf(sq);
    } else if (tid == 64) {
      s_misc[1] = aload(betab + n);
    }
    __syncthreads();
    // scores: 2 threads per i-row (c_x plain/cached read)
    {
      const int row = tid >> 1, half = tid & 1;
      const float* xp = cxt + row * C2D + half * 128;
      const float* kp = s_k + half * 128;
      float np = 0, cp = 0;
#pragma unroll
      for (int x = 0; x < 32; ++x) {
        const float4 xv = *(const float4*)(xp + x * 4);
        np += dot4f(xv, *(const float4*)(kp + x * 4));
        cp += dot4f(xv, xv);
      }
      np += __shfl_xor(np, 1);
      cp += __shfl_xor(cp, 1);
      if (half == 0)
        s_sc[row] = s_misc[1] * np / fmaxf(sqrtf(cp) * s_misc[0], 1e-8f);
    }
    __syncthreads();
    // softmax over 128 (wave 0); final w -> LDS + plain store for cscan
    if (tid < 64) {
      const float a = s_sc[tid], b = s_sc[tid + 64];
      float mx = fmaxf(a, b);
#pragma unroll
      for (int m = 1; m < 64; m <<= 1) mx = fmaxf(mx, __shfl_xor(mx, m));
      const float p0 = __expf(a - mx), p1 = __expf(b - mx);
      float L = p0 + p1;
#pragma unroll
      for (int m = 1; m < 64; m <<= 1) L += __shfl_xor(L, m);
      const float iL = 1.f / L;
      const float w0 = p0 * iL, w1 = p1 * iL;
      s_w[tid] = w0;
      s_w[tid + 64] = w1;
      wbuf[(size_t)(n * TSTEPS + t) * C1D + tid] = w0;
      wbuf[(size_t)(n * TSTEPS + t) * C1D + tid + 64] = w1;
    }
    __syncthreads();
    // r[c] = sum_i w_i * cx[i,c] (second pass, L2-resident)
    {
      const int c = tid;
      float acc = 0.f;
#pragma unroll 8
      for (int i = 0; i < C1D; ++i) acc += s_w[i] * cxt[i * C2D + c];
      astore(rbuf + n * C2D + c, acc);
    }
  };

  // ---- Phase B: GRU, 4 features x 32 batches ----
  auto phase_gru = [&](const float* __restrict__ hsrc, float* __restrict__ hdst, int t) {
#pragma unroll
    for (int idx = tid; idx < 2048; idx += 256) {
      const int n2 = idx >> 6, c4 = (idx & 63) * 4;
      const float4 rv = aload4(rbuf + n2 * C2D + c4);
      *(float4*)(s_r + n2 * 264 + c4) = rv;
    }
    __syncthreads();
    const int n = tid >> 3, s = tid & 7;
    float aR[4] = {0, 0, 0, 0}, aZ[4] = {0, 0, 0, 0};
    float aNi[4] = {0, 0, 0, 0}, aNh[4] = {0, 0, 0, 0};
    const float* rb = s_r + n * 264 + s * 32;
#pragma unroll
    for (int x = 0; x < 8; ++x) {
      const int o = (4 * x + 4 * s) & 31;
      const float4 rv = *(const float4*)(rb + o);
      const int cix = s * 32 + o;
#pragma unroll
      for (int f = 0; f < 4; ++f) {
        aR[f]  += dot4f(rv, *(const float4*)(s_wih + (f * 3 + 0) * 260 + cix));
        aZ[f]  += dot4f(rv, *(const float4*)(s_wih + (f * 3 + 1) * 260 + cix));
        aNi[f] += dot4f(rv, *(const float4*)(s_wih + (f * 3 + 2) * 260 + cix));
      }
    }
    const float* hb = hsrc + n * HD;
#pragma unroll
    for (int x = 0; x < 16; ++x) {
      const int cix = s * 64 + ((4 * x + 8 * s) & 63);
      const float4 hv = aload4(hb + cix);
#pragma unroll
      for (int f = 0; f < 4; ++f) {
        aR[f]  += dot4f(hv, *(const float4*)(s_whh + (f * 3 + 0) * 516 + cix));
        aZ[f]  += dot4f(hv, *(const float4*)(s_whh + (f * 3 + 1) * 516 + cix));
        aNh[f] += dot4f(hv, *(const float4*)(s_whh + (f * 3 + 2) * 516 + cix));
      }
    }
#pragma unroll
    for (int m = 1; m < 8; m <<= 1) {
#pragma unroll
      for (int f = 0; f < 4; ++f) {
        aR[f] += __shfl_xor(aR[f], m);
        aZ[f] += __shfl_xor(aZ[f], m);
        aNi[f] += __shfl_xor(aNi[f], m);
        aNh[f] += __shfl_xor(aNh[f], m);
      }
    }
    if (s == 0) {
      const float4 hp4 = aload4(hsrc + n * HD + j0);
      const float hpv[4] = {hp4.x, hp4.y, hp4.z, hp4.w};
      float hn[4];
#pragma unroll
      for (int f = 0; f < 4; ++f) {
        const int j = j0 + f;
        const float rg = sigm(aR[f] + bih[j] + bhh[j]);
        const float z = sigm(aZ[f] + bih[HD + j] + bhh[HD + j]);
        const float ng = tanhf(aNi[f] + bih[2 * HD + j] + rg * (aNh[f] + bhh[2 * HD + j]));
        hn[f] = (1.f - z) * ng + z * hpv[f];
      }
      astore2(hdst + n * HD + j0, hn[0], hn[1]);
      astore2(hdst + n * HD + j0 + 2, hn[2], hn[3]);
      *(float4*)(hs_out + (size_t)(n * TSTEPS + t) * HD + j0) =
          make_float4(hn[0], hn[1], hn[2], hn[3]);  // plain (host-read)
    }
  };

  // ================= main =================
  proj_k(h0);  // k_0, beta_0
  gridbar();
  for (int t = 0; t < TSTEPS; ++t) {
    const float* hsrc = (t == 0) ? h0 : ((t & 1) ? hb0 : hb1);
    float* hdst = (t & 1) ? hb1 : hb0;
    if (bid < 32) phase_attn(t);
    else if (bid < 96 && t > 0) phase_ev(hsrc, t - 1);  // e,v off critical path
    gridbar();
    phase_gru(hsrc, hdst, t);
    gridbar();
    if (t < TSTEPS - 1) {
      proj_k(hdst);
      gridbar();
    }
  }
  if (bid >= 32 && bid < 96) phase_ev(hb1, TSTEPS - 1);  // tail e,v
}

// ---- parallel c-scan: c_t = c_{t-1}*(1 - w_t e_t) + w_t v_t ----
__global__ void __launch_bounds__(256) ntm_cscan(
    const float* __restrict__ c0, const float* __restrict__ wsf,
    float* __restrict__ out)
{
  const float* wbuf = wsf + 2 * NBAT * HD + NBAT * C2D + 64 + NBAT * C2D;
  const float* earr = wbuf + NBAT * TSTEPS * C1D;
  const float* varr = earr + NBAT * TSTEPS * C2D;
  float* cs_out = out + NBAT * TSTEPS * HD;

  const int tid = threadIdx.x;
  const int lane = tid & 63, wid = tid >> 6;
  const int n = blockIdx.x >> 3, g = blockIdx.x & 7;
  const int i0 = g * 16 + wid * 4;

  f32x4 c[4];
#pragma unroll
  for (int r = 0; r < 4; ++r)
    c[r] = *(const f32x4*)(c0 + ((size_t)(n * C1D + i0 + r)) * C2D + lane * 4);

  const float* ep = earr + (size_t)n * TSTEPS * C2D + lane * 4;
  const float* vp = varr + (size_t)n * TSTEPS * C2D + lane * 4;
  const float* wp = wbuf + (size_t)n * TSTEPS * C1D + i0;

  f32x4 e_nxt = *(const f32x4*)(ep);
  f32x4 v_nxt = *(const f32x4*)(vp);
  for (int t = 0; t < TSTEPS; ++t) {
    const f32x4 e4 = e_nxt, v4 = v_nxt;
    if (t + 1 < TSTEPS) {
      e_nxt = *(const f32x4*)(ep + (t + 1) * C2D);
      v_nxt = *(const f32x4*)(vp + (t + 1) * C2D);
    }
#pragma unroll
    for (int r = 0; r < 4; ++r) {
      const float wr = wp[t * C1D + r];
      c[r] = c[r] * (1.f - wr * e4) + wr * v4;
      __builtin_nontemporal_store(
          c[r], (f32x4*)(cs_out + ((size_t)((n * TSTEPS + t) * C1D + i0 + r)) * C2D + lane * 4));
    }
  }
}

extern "C" void kernel_launch(void* const* d_in, const int* in_sizes, int n_in,
                              void* d_out, int out_size, void* d_ws, size_t ws_size,
                              hipStream_t stream) {
  const float* h0 = (const float*)d_in[0];
  const float* c0 = (const float*)d_in[1];
  const float* c_x = (const float*)d_in[2];
  const float* Wk = (const float*)d_in[3];
  const float* bk = (const float*)d_in[4];
  const float* Wb = (const float*)d_in[5];
  const float* bb = (const float*)d_in[6];
  const float* We = (const float*)d_in[7];
  const float* be = (const float*)d_in[8];
  const float* Wv = (const float*)d_in[9];
  const float* bv = (const float*)d_in[10];
  const float* Wih = (const float*)d_in[11];
  const float* bih = (const float*)d_in[12];
  const float* Whh = (const float*)d_in[13];
  const float* bhh = (const float*)d_in[14];

  unsigned* flags = (unsigned*)d_ws;
  float* wsf = (float*)((char*)d_ws + 16384);

  (void)hipMemsetAsync(d_ws, 0, 16384, stream);  // reset barrier flags (deterministic replay)
  ntm_chain<<<dim3(NBLK), dim3(256), 0, stream>>>(h0, c_x, Wk, bk, Wb, bb, We, be, Wv, bv,
                                                  Wih, bih, Whh, bhh, (float*)d_out, wsf, flags);
  ntm_cscan<<<dim3(256), dim3(256), 0, stream>>>(c0, wsf, (float*)d_out);
}

// Round 8
// 2791.443 us; speedup vs baseline: 4.3178x; 1.0968x over previous
//
#include <hip/hip_runtime.h>
#include <math.h>

// NTM chain: 128 blocks x 256 threads, ZERO global barriers — fine-grained
// dataflow flags (monotonic per-producer counters in LLC, polled uncached).
// Per step t, per block:
//   wait pflag[all]   -> ATTN octant (from LDS tile, prefetched last step)
//   (combine blocks)     wait 3 sibling oflags -> combine softmax+r -> rflag
//   commit tile(t+1) -> wait rflag[0..31] -> GRU (LDS weights) -> hflag
//   wait hflag[all]  -> proj k/beta -> pflag ; blocks 32..95: e,v (off path)
// Cross-block payloads via agent-scope relaxed atomics (LLC-coherent, no
// fences); bulk streams (wbuf/earr/varr/hs) plain cached stores (kernel-end
// writeback feeds the cscan kernel).  cscan: parallel scan, streams 268 MB.
// Shapes: N=32, T=64, C1=128, C2=256, H=512 (all f32).

#define NBAT 32
#define TSTEPS 64
#define C1D 128
#define C2D 256
#define HD 512
#define NBLK 128
#define LN2F 0.6931471805599453f
#define PSTRIDE 296  // partial record: [0]=m,[1]=l,[2..257]=racc,[258..289]=scores

typedef float f32x4 __attribute__((ext_vector_type(4)));

static __device__ __forceinline__ float dot4f(float4 a, float4 b) {
  return a.x * b.x + a.y * b.y + a.z * b.z + a.w * b.w;
}
static __device__ __forceinline__ float sigm(float x) { return 1.0f / (1.0f + __expf(-x)); }

static __device__ __forceinline__ float aload(const float* p) {
  return __hip_atomic_load(p, __ATOMIC_RELAXED, __HIP_MEMORY_SCOPE_AGENT);
}
static __device__ __forceinline__ void astore(float* p, float v) {
  __hip_atomic_store(p, v, __ATOMIC_RELAXED, __HIP_MEMORY_SCOPE_AGENT);
}
static __device__ __forceinline__ float2 aload2(const float* p) {
  unsigned long long u = __hip_atomic_load((const unsigned long long*)p,
                                           __ATOMIC_RELAXED, __HIP_MEMORY_SCOPE_AGENT);
  union { unsigned long long u; float2 f; } c;
  c.u = u;
  return c.f;
}
static __device__ __forceinline__ void astore2(float* p, float a, float b) {
  union { float f[2]; unsigned long long u; } c;
  c.f[0] = a; c.f[1] = b;
  __hip_atomic_store((unsigned long long*)p, c.u, __ATOMIC_RELAXED, __HIP_MEMORY_SCOPE_AGENT);
}
static __device__ __forceinline__ float4 aload4(const float* p) {
  const float2 lo = aload2(p), hi = aload2(p + 2);
  return make_float4(lo.x, lo.y, hi.x, hi.y);
}
static __device__ __forceinline__ unsigned aloadu(const unsigned* p) {
  return __hip_atomic_load(p, __ATOMIC_RELAXED, __HIP_MEMORY_SCOPE_AGENT);
}
static __device__ __forceinline__ void astoreu(unsigned* p, unsigned v) {
  __hip_atomic_store(p, v, __ATOMIC_RELAXED, __HIP_MEMORY_SCOPE_AGENT);
}
static __device__ __forceinline__ void spinu(const unsigned* p, unsigned tgt) {
  while (aloadu(p) < tgt) __builtin_amdgcn_s_sleep(4);
}

#define BLOCK_FENCE() \
  do { asm volatile("s_waitcnt vmcnt(0) lgkmcnt(0)" ::: "memory"); __syncthreads(); } while (0)

__global__ void __launch_bounds__(256) ntm_chain(
    const float* __restrict__ h0, const float* __restrict__ c_x,
    const float* __restrict__ Wk, const float* __restrict__ bk,
    const float* __restrict__ Wb, const float* __restrict__ bb,
    const float* __restrict__ We, const float* __restrict__ be,
    const float* __restrict__ Wv, const float* __restrict__ bv,
    const float* __restrict__ Wih, const float* __restrict__ bih,
    const float* __restrict__ Whh, const float* __restrict__ bhh,
    float* __restrict__ hs_out, float* __restrict__ wsf, unsigned* __restrict__ flags)
{
  const int tid = threadIdx.x;
  const int bid = blockIdx.x;
  const int lane = tid & 63;
  const int wid = tid >> 6;

  // flag index map (each flag on its own 128B line):
  //   pflag[b]=b, oflag[b]=128+b, rflag[n]=256+n, hflag[b]=288+b
  // ---- workspace (floats) ----
  float* hb0   = wsf;                       // [32*512] h buffers (uncached payload)
  float* hb1   = hb0 + NBAT * HD;
  float* kbuf  = hb1 + NBAT * HD;           // [32*256]
  float* betab = kbuf + NBAT * C2D;         // [64]
  float* rbuf  = betab + 64;                // [32*256]
  float* part  = rbuf + NBAT * C2D;         // [32*4*PSTRIDE] attn octant partials
  float* wbuf  = part + NBAT * 4 * PSTRIDE; // [32*64*128] plain
  float* earr  = wbuf + NBAT * TSTEPS * C1D;   // plain
  float* varr  = earr + NBAT * TSTEPS * C2D;   // plain

  // ---- LDS (~125 KB) ----
  __shared__ float s_tile[32 * C2D];  // c_x octant tile (32 rows)
  __shared__ float s_r[NBAT * 264];   // staged r for GRU
  __shared__ float s_wih[12 * 260];
  __shared__ float s_whh[12 * 516];
  __shared__ float s_wk[2 * 516];
  __shared__ float s_wev[8 * 516];
  __shared__ float s_wb[HD];
  __shared__ float s_k[C2D];
  __shared__ float s_sc[32];
  __shared__ float s_p[32];
  __shared__ float s_ml[8];
  __shared__ float s_misc[8];

  const int n_att = bid >> 2, q_att = bid & 3;
  const int j0 = bid * 4;
  const int kch = bid * 2;
  const int evch = (bid - 32) * 4;

  // ---- one-time LDS weight staging ----
  for (int idx = tid; idx < 12 * C2D; idx += 256) {
    const int row = idx >> 8, c = idx & (C2D - 1);
    const int f = row / 3, g = row % 3;
    s_wih[row * 260 + c] = Wih[(g * HD + j0 + f) * C2D + c];
  }
  for (int idx = tid; idx < 12 * HD; idx += 256) {
    const int row = idx >> 9, c = idx & (HD - 1);
    const int f = row / 3, g = row % 3;
    s_whh[row * 516 + c] = Whh[(g * HD + j0 + f) * HD + c];
  }
  for (int idx = tid; idx < 2 * HD; idx += 256) {
    const int row = idx >> 9, c = idx & (HD - 1);
    s_wk[row * 516 + c] = Wk[(kch + row) * HD + c];
  }
  if (bid >= 32 && bid < 96) {
    for (int idx = tid; idx < 8 * HD; idx += 256) {
      const int row = idx >> 9, c = idx & (HD - 1);
      const float* __restrict__ src = (row < 4) ? We : Wv;
      s_wev[row * 516 + c] = src[(evch + (row & 3)) * HD + c];
    }
  }
  for (int idx = tid; idx < HD; idx += 256) s_wb[idx] = Wb[idx];

  // c_x prefetch regs
  float4 pf[8];
  auto prefetch_issue = [&](int t) {
    const float* src = c_x + ((size_t)((n_att * TSTEPS + t) * C1D + q_att * 32)) * C2D + lane * 4;
#pragma unroll
    for (int k = 0; k < 8; ++k) pf[k] = *(const float4*)(src + (wid * 8 + k) * C2D);
  };
  auto prefetch_commit = [&]() {
#pragma unroll
    for (int k = 0; k < 8; ++k) *(float4*)(s_tile + (wid * 8 + k) * C2D + lane * 4) = pf[k];
  };

  // ---- proj: k (2ch) + beta(block0) from hsrc (uncached/cached reads) ----
  auto proj_k = [&](const float* __restrict__ hsrc) {
    const int n = tid >> 3, s = tid & 7;
    const float* hp = hsrc + n * HD;
    float k0 = 0, k1 = 0, bp = 0;
#pragma unroll
    for (int x = 0; x < 16; ++x) {
      const int cix = s * 64 + ((4 * x + 8 * s) & 63);
      const float4 hv = aload4(hp + cix);
      k0 += dot4f(hv, *(const float4*)(s_wk + cix));
      k1 += dot4f(hv, *(const float4*)(s_wk + 516 + cix));
      if (bid == 0) bp += dot4f(hv, *(const float4*)(s_wb + cix));
    }
#pragma unroll
    for (int m = 1; m < 8; m <<= 1) { k0 += __shfl_xor(k0, m); k1 += __shfl_xor(k1, m); }
    if (bid == 0) {
#pragma unroll
      for (int m = 1; m < 8; m <<= 1) bp += __shfl_xor(bp, m);
    }
    if (s == 0) {
      astore2(kbuf + n * C2D + kch, k0 + bk[kch], k1 + bk[kch + 1]);
      if (bid == 0) {
        const float xb = bp + bb[0];
        const float bpos = fmaxf(xb, 0.f), bneg = fminf(xb, 0.f);
        astore(betab + n, log1pf(__expf(bneg)) + bpos + log1pf(__expf(-bpos)) + (1.0f - LN2F));
      }
    }
  };

  // ---- e,v for step t from hsrc (blocks 32..95) ----
  auto phase_ev = [&](const float* __restrict__ hsrc, int te) {
    const int n = tid >> 3, s = tid & 7;
    const float* hp = hsrc + n * HD;
    float e[4] = {0, 0, 0, 0}, v[4] = {0, 0, 0, 0};
#pragma unroll
    for (int x = 0; x < 16; ++x) {
      const int cix = s * 64 + ((4 * x + 8 * s) & 63);
      const float4 hv = aload4(hp + cix);
#pragma unroll
      for (int f = 0; f < 4; ++f) {
        e[f] += dot4f(hv, *(const float4*)(s_wev + f * 516 + cix));
        v[f] += dot4f(hv, *(const float4*)(s_wev + (4 + f) * 516 + cix));
      }
    }
#pragma unroll
    for (int m = 1; m < 8; m <<= 1) {
#pragma unroll
      for (int f = 0; f < 4; ++f) { e[f] += __shfl_xor(e[f], m); v[f] += __shfl_xor(v[f], m); }
    }
    if (s == 0) {
      *(float4*)(earr + (size_t)(n * TSTEPS + te) * C2D + evch) =
          make_float4(sigm(e[0] + be[evch]), sigm(e[1] + be[evch + 1]),
                      sigm(e[2] + be[evch + 2]), sigm(e[3] + be[evch + 3]));
      *(float4*)(varr + (size_t)(n * TSTEPS + te) * C2D + evch) =
          make_float4(v[0] + bv[evch], v[1] + bv[evch + 1],
                      v[2] + bv[evch + 2], v[3] + bv[evch + 3]);
    }
  };

  // ---- ATTN octant from LDS tile -> partial (m,l,racc,scores) -> oflag ----
  auto phase_attn = [&](int t) {
    if (tid < 64) {
      const float4 kv = aload4(kbuf + n_att * C2D + tid * 4);
      *(float4*)(s_k + tid * 4) = kv;
      float sq = kv.x * kv.x + kv.y * kv.y + kv.z * kv.z + kv.w * kv.w;
#pragma unroll
      for (int m = 1; m < 64; m <<= 1) sq += __shfl_xor(sq, m);
      if (tid == 0) s_misc[0] = sqrtf(sq);
    } else if (tid == 64) {
      s_misc[1] = aload(betab + n_att);
    }
    __syncthreads();
    {
      const int row = tid >> 3, s8 = tid & 7;
      const float* xp = s_tile + row * C2D + s8 * 32;
      const float* kp = s_k + s8 * 32;
      float np = 0, cp = 0;
#pragma unroll
      for (int x = 0; x < 8; ++x) {
        const float4 xv = *(const float4*)(xp + x * 4);
        np += dot4f(xv, *(const float4*)(kp + x * 4));
        cp += dot4f(xv, xv);
      }
      np += __shfl_xor(np, 1); cp += __shfl_xor(cp, 1);
      np += __shfl_xor(np, 2); cp += __shfl_xor(cp, 2);
      np += __shfl_xor(np, 4); cp += __shfl_xor(cp, 4);
      if (s8 == 0) s_sc[row] = s_misc[1] * np / fmaxf(sqrtf(cp) * s_misc[0], 1e-8f);
    }
    __syncthreads();
    float* pp = part + (size_t)(n_att * 4 + q_att) * PSTRIDE;
    if (tid < 32) {
      const float s = s_sc[tid];
      float mq = s;
#pragma unroll
      for (int m = 1; m < 32; m <<= 1) mq = fmaxf(mq, __shfl_xor(mq, m));
      const float p = __expf(s - mq);
      s_p[tid] = p;
      float lq = p;
#pragma unroll
      for (int m = 1; m < 32; m <<= 1) lq += __shfl_xor(lq, m);
      if (tid == 0) astore2(pp, mq, lq);
      astore(pp + 258 + tid, s);
    }
    __syncthreads();
    {
      const int c = tid;
      float acc = 0.f;
#pragma unroll 8
      for (int i = 0; i < 32; ++i) acc += s_p[i] * s_tile[i * C2D + c];
      astore(pp + 2 + c, acc);
    }
    BLOCK_FENCE();
    if (tid == 0) astoreu(flags + (128 + bid) * 32, (unsigned)(t + 1));
  };

  // ---- combine (blocks with q==0): softmax finalize + r -> rflag ----
  auto phase_combine = [&](int t) {
    const int n = bid >> 2;
    if (tid < 3) spinu(flags + (128 + bid + 1 + tid) * 32, (unsigned)(t + 1));
    __syncthreads();
    if (tid < 4) {
      const float2 ml = aload2(part + (size_t)(n * 4 + tid) * PSTRIDE);
      s_ml[2 * tid] = ml.x; s_ml[2 * tid + 1] = ml.y;
    }
    __syncthreads();
    const float M = fmaxf(fmaxf(s_ml[0], s_ml[2]), fmaxf(s_ml[4], s_ml[6]));
    const float sc0 = __expf(s_ml[0] - M), sc1 = __expf(s_ml[2] - M);
    const float sc2 = __expf(s_ml[4] - M), sc3 = __expf(s_ml[6] - M);
    const float invL = 1.f / (s_ml[1] * sc0 + s_ml[3] * sc1 + s_ml[5] * sc2 + s_ml[7] * sc3);
    if (tid < 128) {
      const int q = tid >> 5, i = tid & 31;
      const float s = aload(part + (size_t)(n * 4 + q) * PSTRIDE + 258 + i);
      wbuf[((size_t)n * TSTEPS + t) * C1D + tid] = __expf(s - M) * invL;  // plain
    }
    {
      const int c = tid;
      const float r = (sc0 * aload(part + (size_t)(n * 4 + 0) * PSTRIDE + 2 + c) +
                       sc1 * aload(part + (size_t)(n * 4 + 1) * PSTRIDE + 2 + c) +
                       sc2 * aload(part + (size_t)(n * 4 + 2) * PSTRIDE + 2 + c) +
                       sc3 * aload(part + (size_t)(n * 4 + 3) * PSTRIDE + 2 + c)) * invL;
      astore(rbuf + n * C2D + c, r);
    }
    BLOCK_FENCE();
    if (tid == 0) astoreu(flags + (256 + n) * 32, (unsigned)(t + 1));
  };

  // ---- GRU: 4 features x 32 batches -> hflag ----
  auto phase_gru = [&](const float* __restrict__ hsrc, float* __restrict__ hdst, int t) {
#pragma unroll
    for (int idx = tid; idx < 2048; idx += 256) {
      const int n2 = idx >> 6, c4 = (idx & 63) * 4;
      const float4 rv = aload4(rbuf + n2 * C2D + c4);
      *(float4*)(s_r + n2 * 264 + c4) = rv;
    }
    __syncthreads();
    const int n = tid >> 3, s = tid & 7;
    float aR[4] = {0, 0, 0, 0}, aZ[4] = {0, 0, 0, 0};
    float aNi[4] = {0, 0, 0, 0}, aNh[4] = {0, 0, 0, 0};
    const float* rb = s_r + n * 264 + s * 32;
#pragma unroll
    for (int x = 0; x < 8; ++x) {
      const int o = (4 * x + 4 * s) & 31;
      const float4 rv = *(const float4*)(rb + o);
      const int cix = s * 32 + o;
#pragma unroll
      for (int f = 0; f < 4; ++f) {
        aR[f]  += dot4f(rv, *(const float4*)(s_wih + (f * 3 + 0) * 260 + cix));
        aZ[f]  += dot4f(rv, *(const float4*)(s_wih + (f * 3 + 1) * 260 + cix));
        aNi[f] += dot4f(rv, *(const float4*)(s_wih + (f * 3 + 2) * 260 + cix));
      }
    }
    const float* hb = hsrc + n * HD;
#pragma unroll
    for (int x = 0; x < 16; ++x) {
      const int cix = s * 64 + ((4 * x + 8 * s) & 63);
      const float4 hv = aload4(hb + cix);
#pragma unroll
      for (int f = 0; f < 4; ++f) {
        aR[f]  += dot4f(hv, *(const float4*)(s_whh + (f * 3 + 0) * 516 + cix));
        aZ[f]  += dot4f(hv, *(const float4*)(s_whh + (f * 3 + 1) * 516 + cix));
        aNh[f] += dot4f(hv, *(const float4*)(s_whh + (f * 3 + 2) * 516 + cix));
      }
    }
#pragma unroll
    for (int m = 1; m < 8; m <<= 1) {
#pragma unroll
      for (int f = 0; f < 4; ++f) {
        aR[f] += __shfl_xor(aR[f], m);
        aZ[f] += __shfl_xor(aZ[f], m);
        aNi[f] += __shfl_xor(aNi[f], m);
        aNh[f] += __shfl_xor(aNh[f], m);
      }
    }
    if (s == 0) {
      const float4 hp4 = aload4(hsrc + n * HD + j0);
      const float hpv[4] = {hp4.x, hp4.y, hp4.z, hp4.w};
      float hn[4];
#pragma unroll
      for (int f = 0; f < 4; ++f) {
        const int j = j0 + f;
        const float rg = sigm(aR[f] + bih[j] + bhh[j]);
        const float z = sigm(aZ[f] + bih[HD + j] + bhh[HD + j]);
        const float ng = tanhf(aNi[f] + bih[2 * HD + j] + rg * (aNh[f] + bhh[2 * HD + j]));
        hn[f] = (1.f - z) * ng + z * hpv[f];
      }
      astore2(hdst + n * HD + j0, hn[0], hn[1]);
      astore2(hdst + n * HD + j0 + 2, hn[2], hn[3]);
      *(float4*)(hs_out + (size_t)(n * TSTEPS + t) * HD + j0) =
          make_float4(hn[0], hn[1], hn[2], hn[3]);  // plain (host)
    }
    BLOCK_FENCE();
    if (tid == 0) astoreu(flags + (288 + bid) * 32, (unsigned)(t + 1));
  };

  // ================= prologue =================
  // copy h0 -> hb1 (uncached payload), tile(0) prefetch, proj(h0) -> pflag=1
  if (tid < 64) {
    const int base = bid * 128 + tid * 2;
    astore2(hb1 + base, h0[base], h0[base + 1]);
  }
  prefetch_issue(0);
  __syncthreads();  // weights + s_tile staging visible
  prefetch_commit();
  proj_k(h0);
  BLOCK_FENCE();
  if (tid == 0) astoreu(flags + bid * 32, 1u);

  // ================= main loop =================
  for (int t = 0; t < TSTEPS; ++t) {
    const float* hsrc = (t & 1) ? hb0 : hb1;
    float* hdst = (t & 1) ? hb1 : hb0;
    // wait k(t): all proj producers
    if (tid < 64) {
      spinu(flags + (2 * tid) * 32, (unsigned)(t + 1));
      spinu(flags + (2 * tid + 1) * 32, (unsigned)(t + 1));
    }
    __syncthreads();
    phase_attn(t);
    if (t < TSTEPS - 1) prefetch_issue(t + 1);
    if ((bid & 3) == 0) phase_combine(t);
    if (t < TSTEPS - 1) prefetch_commit();
    // wait r
    if (tid < 32) spinu(flags + (256 + tid) * 32, (unsigned)(t + 1));
    __syncthreads();
    phase_gru(hsrc, hdst, t);
    // wait full h
    if (tid < 64) {
      spinu(flags + (288 + 2 * tid) * 32, (unsigned)(t + 1));
      spinu(flags + (288 + 2 * tid + 1) * 32, (unsigned)(t + 1));
    }
    __syncthreads();
    if (t < TSTEPS - 1) {
      proj_k(hdst);
      BLOCK_FENCE();
      if (tid == 0) astoreu(flags + bid * 32, (unsigned)(t + 2));
    }
    if (bid >= 32 && bid < 96) phase_ev(hdst, t);  // off critical path
  }
}

// ---- parallel c-scan: c_t = c_{t-1}*(1 - w_t e_t) + w_t v_t ----
__global__ void __launch_bounds__(256) ntm_cscan(
    const float* __restrict__ c0, const float* __restrict__ wsf,
    float* __restrict__ out)
{
  const float* wbuf = wsf + 2 * NBAT * HD + NBAT * C2D + 64 + NBAT * C2D + NBAT * 4 * PSTRIDE;
  const float* earr = wbuf + NBAT * TSTEPS * C1D;
  const float* varr = earr + NBAT * TSTEPS * C2D;
  float* cs_out = out + NBAT * TSTEPS * HD;

  const int tid = threadIdx.x;
  const int lane = tid & 63, wid = tid >> 6;
  const int n = blockIdx.x >> 3, g = blockIdx.x & 7;
  const int i0 = g * 16 + wid * 4;

  f32x4 c[4];
#pragma unroll
  for (int r = 0; r < 4; ++r)
    c[r] = *(const f32x4*)(c0 + ((size_t)(n * C1D + i0 + r)) * C2D + lane * 4);

  const float* ep = earr + (size_t)n * TSTEPS * C2D + lane * 4;
  const float* vp = varr + (size_t)n * TSTEPS * C2D + lane * 4;
  const float* wp = wbuf + (size_t)n * TSTEPS * C1D + i0;

  f32x4 e_nxt = *(const f32x4*)(ep);
  f32x4 v_nxt = *(const f32x4*)(vp);
  for (int t = 0; t < TSTEPS; ++t) {
    const f32x4 e4 = e_nxt, v4 = v_nxt;
    if (t + 1 < TSTEPS) {
      e_nxt = *(const f32x4*)(ep + (t + 1) * C2D);
      v_nxt = *(const f32x4*)(vp + (t + 1) * C2D);
    }
#pragma unroll
    for (int r = 0; r < 4; ++r) {
      const float wr = wp[t * C1D + r];
      c[r] = c[r] * (1.f - wr * e4) + wr * v4;
      __builtin_nontemporal_store(
          c[r], (f32x4*)(cs_out + ((size_t)((n * TSTEPS + t) * C1D + i0 + r)) * C2D + lane * 4));
    }
  }
}

extern "C" void kernel_launch(void* const* d_in, const int* in_sizes, int n_in,
                              void* d_out, int out_size, void* d_ws, size_t ws_size,
                              hipStream_t stream) {
  const float* h0 = (const float*)d_in[0];
  const float* c0 = (const float*)d_in[1];
  const float* c_x = (const float*)d_in[2];
  const float* Wk = (const float*)d_in[3];
  const float* bk = (const float*)d_in[4];
  const float* Wb = (const float*)d_in[5];
  const float* bb = (const float*)d_in[6];
  const float* We = (const float*)d_in[7];
  const float* be = (const float*)d_in[8];
  const float* Wv = (const float*)d_in[9];
  const float* bv = (const float*)d_in[10];
  const float* Wih = (const float*)d_in[11];
  const float* bih = (const float*)d_in[12];
  const float* Whh = (const float*)d_in[13];
  const float* bhh = (const float*)d_in[14];

  unsigned* flags = (unsigned*)d_ws;
  float* wsf = (float*)((char*)d_ws + 65536);

  (void)hipMemsetAsync(d_ws, 0, 65536, stream);  // reset flags (deterministic replay)
  ntm_chain<<<dim3(NBLK), dim3(256), 0, stream>>>(h0, c_x, Wk, bk, Wb, bb, We, be, Wv, bv,
                                                  Wih, bih, Whh, bhh, (float*)d_out, wsf, flags);
  ntm_cscan<<<dim3(256), dim3(256), 0, stream>>>(c0, wsf, (float*)d_out);
}

// Round 9
// 2683.741 us; speedup vs baseline: 4.4911x; 1.0401x over previous
//
#include <hip/hip_runtime.h>
#include <math.h>

// NTM chain: 128 blocks x 256 threads, 3 dataflow hops/step with hierarchical
// arrive (8 interim lines -> 1 final -> 16 replicated release lines) and
// single-thread polling (kills the LLC poll storm).
//  hop P: proj(t) k,beta ready -> attn(t)
//  hop A: all 128 attn octants done -> GRU (GRU merges octant partials inline)
//  hop H: all h_t written -> proj(t+1)
// e,v matvecs: 2 channels on every block, in the post-arrive slack window.
// Payloads via agent-scope relaxed atomics (LLC-coherent, fence-free); bulk
// streams (wbuf/earr/varr/hs) plain cached stores (kernel-end writeback feeds
// cscan).  cscan: parallel scan c_t = c_{t-1}(1-w_t e_t) + w_t v_t, 268 MB.
// Shapes: N=32, T=64, C1=128, C2=256, H=512 (all f32).

#define NBAT 32
#define TSTEPS 64
#define C1D 128
#define C2D 256
#define HD 512
#define NBLK 128
#define LN2F 0.6931471805599453f
#define PSTRIDE 296  // partial record: [0]=m,[1]=l,[2..257]=racc,[258..289]=scores

typedef float f32x4 __attribute__((ext_vector_type(4)));

static __device__ __forceinline__ float dot4f(float4 a, float4 b) {
  return a.x * b.x + a.y * b.y + a.z * b.z + a.w * b.w;
}
static __device__ __forceinline__ float sigm(float x) { return 1.0f / (1.0f + __expf(-x)); }

static __device__ __forceinline__ float aload(const float* p) {
  return __hip_atomic_load(p, __ATOMIC_RELAXED, __HIP_MEMORY_SCOPE_AGENT);
}
static __device__ __forceinline__ void astore(float* p, float v) {
  __hip_atomic_store(p, v, __ATOMIC_RELAXED, __HIP_MEMORY_SCOPE_AGENT);
}
static __device__ __forceinline__ float2 aload2(const float* p) {
  unsigned long long u = __hip_atomic_load((const unsigned long long*)p,
                                           __ATOMIC_RELAXED, __HIP_MEMORY_SCOPE_AGENT);
  union { unsigned long long u; float2 f; } c;
  c.u = u;
  return c.f;
}
static __device__ __forceinline__ void astore2(float* p, float a, float b) {
  union { float f[2]; unsigned long long u; } c;
  c.f[0] = a; c.f[1] = b;
  __hip_atomic_store((unsigned long long*)p, c.u, __ATOMIC_RELAXED, __HIP_MEMORY_SCOPE_AGENT);
}
static __device__ __forceinline__ float4 aload4(const float* p) {
  const float2 lo = aload2(p), hi = aload2(p + 2);
  return make_float4(lo.x, lo.y, hi.x, hi.y);
}
static __device__ __forceinline__ unsigned aloadu(const unsigned* p) {
  return __hip_atomic_load(p, __ATOMIC_RELAXED, __HIP_MEMORY_SCOPE_AGENT);
}
static __device__ __forceinline__ void astoreu(unsigned* p, unsigned v) {
  __hip_atomic_store(p, v, __ATOMIC_RELAXED, __HIP_MEMORY_SCOPE_AGENT);
}

#define BLOCK_FENCE() \
  do { asm volatile("s_waitcnt vmcnt(0) lgkmcnt(0)" ::: "memory"); __syncthreads(); } while (0)

__global__ void __launch_bounds__(256) ntm_chain(
    const float* __restrict__ h0, const float* __restrict__ c_x,
    const float* __restrict__ Wk, const float* __restrict__ bk,
    const float* __restrict__ Wb, const float* __restrict__ bb,
    const float* __restrict__ We, const float* __restrict__ be,
    const float* __restrict__ Wv, const float* __restrict__ bv,
    const float* __restrict__ Wih, const float* __restrict__ bih,
    const float* __restrict__ Whh, const float* __restrict__ bhh,
    float* __restrict__ hs_out, float* __restrict__ wsf, unsigned* __restrict__ flags)
{
  const int tid = threadIdx.x;
  const int bid = blockIdx.x;
  const int lane = tid & 63;
  const int wid = tid >> 6;

  // ---- stage flag sets (each "line" = 32 uints = 128 B) ----
  unsigned* A_int = flags + 0 * 32;   // 8 lines
  unsigned* A_fin = flags + 8 * 32;
  unsigned* A_rel = flags + 16 * 32;  // 16 lines
  unsigned* H_int = flags + 32 * 32;
  unsigned* H_fin = flags + 40 * 32;
  unsigned* H_rel = flags + 48 * 32;
  unsigned* P_int = flags + 64 * 32;
  unsigned* P_fin = flags + 72 * 32;
  unsigned* P_rel = flags + 80 * 32;

  // ---- workspace (floats) ----
  float* hb0   = wsf;                        // [32*512]
  float* hb1   = hb0 + NBAT * HD;            // [32*512]
  float* kbuf  = hb1 + NBAT * HD;            // [32*256]
  float* betab = kbuf + NBAT * C2D;          // [64]
  float* part  = betab + 64;                 // [32*4*PSTRIDE]
  float* wbuf  = part + NBAT * 4 * PSTRIDE;  // [32*64*128] plain
  float* earr  = wbuf + NBAT * TSTEPS * C1D; // [32*64*256] plain
  float* varr  = earr + NBAT * TSTEPS * C2D; // [32*64*256] plain

  // ---- LDS (~120 KB) ----
  __shared__ float s_tile[32 * C2D];  // c_x octant tile
  __shared__ float s_r[NBAT * 264];   // combined r for GRU
  __shared__ float s_wih[12 * 260];
  __shared__ float s_whh[12 * 516];
  __shared__ float s_wk[2 * 516];
  __shared__ float s_wev[4 * 516];    // rows 0-1: We(2ch), 2-3: Wv(2ch)
  __shared__ float s_wb[HD];
  __shared__ float s_k[C2D];
  __shared__ float s_sc[32];
  __shared__ float s_p[32];
  __shared__ float s_scale[192];      // [n*4+q]=exp(mq-M)*invL, [128+n]=M, [160+n]=invL
  __shared__ float s_misc[8];

  const int n_att = bid >> 2, q_att = bid & 3;
  const int j0 = bid * 4;
  const int kch = bid * 2;
  const int evch = bid * 2;

  // ---- one-time LDS weight staging ----
  for (int idx = tid; idx < 12 * C2D; idx += 256) {
    const int row = idx >> 8, c = idx & (C2D - 1);
    const int f = row / 3, g = row % 3;
    s_wih[row * 260 + c] = Wih[(g * HD + j0 + f) * C2D + c];
  }
  for (int idx = tid; idx < 12 * HD; idx += 256) {
    const int row = idx >> 9, c = idx & (HD - 1);
    const int f = row / 3, g = row % 3;
    s_whh[row * 516 + c] = Whh[(g * HD + j0 + f) * HD + c];
  }
  for (int idx = tid; idx < 2 * HD; idx += 256) {
    const int row = idx >> 9, c = idx & (HD - 1);
    s_wk[row * 516 + c] = Wk[(kch + row) * HD + c];
  }
  for (int idx = tid; idx < 4 * HD; idx += 256) {
    const int row = idx >> 9, c = idx & (HD - 1);
    const float* __restrict__ src = (row < 2) ? We : Wv;
    s_wev[row * 516 + c] = src[(evch + (row & 1)) * HD + c];
  }
  for (int idx = tid; idx < HD; idx += 256) s_wb[idx] = Wb[idx];

  // ---- hierarchical arrive / replicated-release wait ----
  auto arrive = [&](unsigned* intr, unsigned* fin, unsigned* rel, unsigned g) {
    if (tid == 0) {
      const unsigned old = __hip_atomic_fetch_add(intr + (bid >> 4) * 32, 1u,
                                                  __ATOMIC_RELAXED, __HIP_MEMORY_SCOPE_AGENT);
      if (old == 16u * g - 1u) {
        const unsigned o2 = __hip_atomic_fetch_add(fin, 1u, __ATOMIC_RELAXED,
                                                   __HIP_MEMORY_SCOPE_AGENT);
        if (o2 == 8u * g - 1u) {
#pragma unroll
          for (int i = 0; i < 16; ++i) astoreu(rel + i * 32, g);
        }
      }
    }
  };
  auto wait_rel = [&](unsigned* rel, unsigned g) {
    if (tid == 0) {
      const unsigned* p = rel + (bid & 15) * 32;
      while (aloadu(p) < g) __builtin_amdgcn_s_sleep(2);
    }
    __syncthreads();
  };

  // ---- c_x prefetch regs ----
  float4 pf[8];
  auto prefetch_issue = [&](int t) {
    const float* src = c_x + ((size_t)((n_att * TSTEPS + t) * C1D + q_att * 32)) * C2D + lane * 4;
#pragma unroll
    for (int k = 0; k < 8; ++k) pf[k] = *(const float4*)(src + (wid * 8 + k) * C2D);
  };
  auto prefetch_commit = [&]() {
#pragma unroll
    for (int k = 0; k < 8; ++k) *(float4*)(s_tile + (wid * 8 + k) * C2D + lane * 4) = pf[k];
  };

  // ---- proj: k (2ch) + beta(block0) ----
  auto proj_k = [&](const float* __restrict__ hsrc) {
    const int n = tid >> 3, s = tid & 7;
    const float* hp = hsrc + n * HD;
    float k0 = 0, k1 = 0, bp = 0;
#pragma unroll
    for (int x = 0; x < 16; ++x) {
      const int cix = s * 64 + ((4 * x + 8 * s) & 63);
      const float4 hv = aload4(hp + cix);
      k0 += dot4f(hv, *(const float4*)(s_wk + cix));
      k1 += dot4f(hv, *(const float4*)(s_wk + 516 + cix));
      if (bid == 0) bp += dot4f(hv, *(const float4*)(s_wb + cix));
    }
#pragma unroll
    for (int m = 1; m < 8; m <<= 1) { k0 += __shfl_xor(k0, m); k1 += __shfl_xor(k1, m); }
    if (bid == 0) {
#pragma unroll
      for (int m = 1; m < 8; m <<= 1) bp += __shfl_xor(bp, m);
    }
    if (s == 0) {
      astore2(kbuf + n * C2D + kch, k0 + bk[kch], k1 + bk[kch + 1]);
      if (bid == 0) {
        const float xb = bp + bb[0];
        const float bpos = fmaxf(xb, 0.f), bneg = fminf(xb, 0.f);
        astore(betab + n, log1pf(__expf(bneg)) + bpos + log1pf(__expf(-bpos)) + (1.0f - LN2F));
      }
    }
  };

  // ---- e,v: 2 channels on every block (plain stores; cscan consumer) ----
  auto phase_ev = [&](const float* __restrict__ hsrc, int te) {
    const int n = tid >> 3, s = tid & 7;
    const float* hp = hsrc + n * HD;
    float e0 = 0, e1 = 0, v0 = 0, v1 = 0;
#pragma unroll
    for (int x = 0; x < 16; ++x) {
      const int cix = s * 64 + ((4 * x + 8 * s) & 63);
      const float4 hv = aload4(hp + cix);
      e0 += dot4f(hv, *(const float4*)(s_wev + cix));
      e1 += dot4f(hv, *(const float4*)(s_wev + 516 + cix));
      v0 += dot4f(hv, *(const float4*)(s_wev + 1032 + cix));
      v1 += dot4f(hv, *(const float4*)(s_wev + 1548 + cix));
    }
#pragma unroll
    for (int m = 1; m < 8; m <<= 1) {
      e0 += __shfl_xor(e0, m); e1 += __shfl_xor(e1, m);
      v0 += __shfl_xor(v0, m); v1 += __shfl_xor(v1, m);
    }
    if (s == 0) {
      *(float2*)(earr + (size_t)(n * TSTEPS + te) * C2D + evch) =
          make_float2(sigm(e0 + be[evch]), sigm(e1 + be[evch + 1]));
      *(float2*)(varr + (size_t)(n * TSTEPS + te) * C2D + evch) =
          make_float2(v0 + bv[evch], v1 + bv[evch + 1]);
    }
  };

  // ---- ATTN octant -> partial record (m,l,racc,scores) ----
  auto phase_attn = [&](int t) {
    if (tid < 64) {
      const float4 kv = aload4(kbuf + n_att * C2D + tid * 4);
      *(float4*)(s_k + tid * 4) = kv;
      float sq = kv.x * kv.x + kv.y * kv.y + kv.z * kv.z + kv.w * kv.w;
#pragma unroll
      for (int m = 1; m < 64; m <<= 1) sq += __shfl_xor(sq, m);
      if (tid == 0) s_misc[0] = sqrtf(sq);
    } else if (tid == 64) {
      s_misc[1] = aload(betab + n_att);
    }
    __syncthreads();
    {
      const int row = tid >> 3, s8 = tid & 7;
      const float* xp = s_tile + row * C2D + s8 * 32;
      const float* kp = s_k + s8 * 32;
      float np = 0, cp = 0;
#pragma unroll
      for (int x = 0; x < 8; ++x) {
        const float4 xv = *(const float4*)(xp + x * 4);
        np += dot4f(xv, *(const float4*)(kp + x * 4));
        cp += dot4f(xv, xv);
      }
      np += __shfl_xor(np, 1); cp += __shfl_xor(cp, 1);
      np += __shfl_xor(np, 2); cp += __shfl_xor(cp, 2);
      np += __shfl_xor(np, 4); cp += __shfl_xor(cp, 4);
      if (s8 == 0) s_sc[row] = s_misc[1] * np / fmaxf(sqrtf(cp) * s_misc[0], 1e-8f);
    }
    __syncthreads();
    float* pp = part + (size_t)(n_att * 4 + q_att) * PSTRIDE;
    if (tid < 32) {
      const float s = s_sc[tid];
      float mq = s;
#pragma unroll
      for (int m = 1; m < 32; m <<= 1) mq = fmaxf(mq, __shfl_xor(mq, m));
      const float p = __expf(s - mq);
      s_p[tid] = p;
      float lq = p;
#pragma unroll
      for (int m = 1; m < 32; m <<= 1) lq += __shfl_xor(lq, m);
      if (tid == 0) astore2(pp, mq, lq);
      astore(pp + 258 + tid, s);
    }
    __syncthreads();
    {
      const int c = tid;
      float acc = 0.f;
#pragma unroll 8
      for (int i = 0; i < 32; ++i) acc += s_p[i] * s_tile[i * C2D + c];
      astore(pp + 2 + c, acc);
    }
  };

  // ---- GRU: inline octant-combine -> s_r; w-finalize (bid<32); matvecs ----
  auto phase_gru = [&](const float* __restrict__ hsrc, float* __restrict__ hdst, int t) {
    if (tid < NBAT) {
      const int n = tid;
      float mq[4], lq[4];
#pragma unroll
      for (int q = 0; q < 4; ++q) {
        const float2 ml = aload2(part + (size_t)(n * 4 + q) * PSTRIDE);
        mq[q] = ml.x; lq[q] = ml.y;
      }
      const float M = fmaxf(fmaxf(mq[0], mq[1]), fmaxf(mq[2], mq[3]));
      float x[4], L = 0.f;
#pragma unroll
      for (int q = 0; q < 4; ++q) { x[q] = __expf(mq[q] - M); L += lq[q] * x[q]; }
      const float invL = 1.f / L;
#pragma unroll
      for (int q = 0; q < 4; ++q) s_scale[n * 4 + q] = x[q] * invL;
      s_scale[128 + n] = M;
      s_scale[160 + n] = invL;
    }
    __syncthreads();
    // combine racc octants -> s_r (reads LLC-hot part records)
    for (int idx = tid; idx < 2048; idx += 256) {
      const int n2 = idx >> 6, c4 = (idx & 63) * 4;
      const float4 r0 = aload4(part + (size_t)(n2 * 4 + 0) * PSTRIDE + 2 + c4);
      const float4 r1 = aload4(part + (size_t)(n2 * 4 + 1) * PSTRIDE + 2 + c4);
      const float4 r2 = aload4(part + (size_t)(n2 * 4 + 2) * PSTRIDE + 2 + c4);
      const float4 r3 = aload4(part + (size_t)(n2 * 4 + 3) * PSTRIDE + 2 + c4);
      const float a0 = s_scale[n2 * 4], a1 = s_scale[n2 * 4 + 1];
      const float a2 = s_scale[n2 * 4 + 2], a3 = s_scale[n2 * 4 + 3];
      *(float4*)(s_r + n2 * 264 + c4) = make_float4(
          a0 * r0.x + a1 * r1.x + a2 * r2.x + a3 * r3.x,
          a0 * r0.y + a1 * r1.y + a2 * r2.y + a3 * r3.y,
          a0 * r0.z + a1 * r1.z + a2 * r2.z + a3 * r3.z,
          a0 * r0.w + a1 * r1.w + a2 * r2.w + a3 * r3.w);
    }
    if (bid < NBAT && tid < 128) {  // finalize w row for n=bid (cscan consumer)
      const int q = tid >> 5, i = tid & 31;
      const float s = aload(part + (size_t)(bid * 4 + q) * PSTRIDE + 258 + i);
      wbuf[((size_t)bid * TSTEPS + t) * C1D + tid] =
          __expf(s - s_scale[128 + bid]) * s_scale[160 + bid];
    }
    __syncthreads();
    const int n = tid >> 3, s = tid & 7;
    float aR[4] = {0, 0, 0, 0}, aZ[4] = {0, 0, 0, 0};
    float aNi[4] = {0, 0, 0, 0}, aNh[4] = {0, 0, 0, 0};
    const float* rb = s_r + n * 264 + s * 32;
#pragma unroll
    for (int x = 0; x < 8; ++x) {
      const int o = (4 * x + 4 * s) & 31;
      const float4 rv = *(const float4*)(rb + o);
      const int cix = s * 32 + o;
#pragma unroll
      for (int f = 0; f < 4; ++f) {
        aR[f]  += dot4f(rv, *(const float4*)(s_wih + (f * 3 + 0) * 260 + cix));
        aZ[f]  += dot4f(rv, *(const float4*)(s_wih + (f * 3 + 1) * 260 + cix));
        aNi[f] += dot4f(rv, *(const float4*)(s_wih + (f * 3 + 2) * 260 + cix));
      }
    }
    const float* hb = hsrc + n * HD;
#pragma unroll
    for (int x = 0; x < 16; ++x) {
      const int cix = s * 64 + ((4 * x + 8 * s) & 63);
      const float4 hv = aload4(hb + cix);
#pragma unroll
      for (int f = 0; f < 4; ++f) {
        aR[f]  += dot4f(hv, *(const float4*)(s_whh + (f * 3 + 0) * 516 + cix));
        aZ[f]  += dot4f(hv, *(const float4*)(s_whh + (f * 3 + 1) * 516 + cix));
        aNh[f] += dot4f(hv, *(const float4*)(s_whh + (f * 3 + 2) * 516 + cix));
      }
    }
#pragma unroll
    for (int m = 1; m < 8; m <<= 1) {
#pragma unroll
      for (int f = 0; f < 4; ++f) {
        aR[f] += __shfl_xor(aR[f], m);
        aZ[f] += __shfl_xor(aZ[f], m);
        aNi[f] += __shfl_xor(aNi[f], m);
        aNh[f] += __shfl_xor(aNh[f], m);
      }
    }
    if (s == 0) {
      const float4 hp4 = aload4(hsrc + n * HD + j0);
      const float hpv[4] = {hp4.x, hp4.y, hp4.z, hp4.w};
      float hn[4];
#pragma unroll
      for (int f = 0; f < 4; ++f) {
        const int j = j0 + f;
        const float rg = sigm(aR[f] + bih[j] + bhh[j]);
        const float z = sigm(aZ[f] + bih[HD + j] + bhh[HD + j]);
        const float ng = tanhf(aNi[f] + bih[2 * HD + j] + rg * (aNh[f] + bhh[2 * HD + j]));
        hn[f] = (1.f - z) * ng + z * hpv[f];
      }
      astore2(hdst + n * HD + j0, hn[0], hn[1]);
      astore2(hdst + n * HD + j0 + 2, hn[2], hn[3]);
      *(float4*)(hs_out + (size_t)(n * TSTEPS + t) * HD + j0) =
          make_float4(hn[0], hn[1], hn[2], hn[3]);  // plain (host)
    }
  };

  // ================= prologue =================
  if (tid < 64) {
    const int base = bid * 128 + tid * 2;
    astore2(hb1 + base, h0[base], h0[base + 1]);
  }
  prefetch_issue(0);
  __syncthreads();
  prefetch_commit();
  proj_k(h0);
  BLOCK_FENCE();
  arrive(P_int, P_fin, P_rel, 1u);

  // ================= main loop =================
  for (int t = 0; t < TSTEPS; ++t) {
    const unsigned g = (unsigned)(t + 1);
    const float* hsrc = (t & 1) ? hb0 : hb1;
    float* hdst = (t & 1) ? hb1 : hb0;

    wait_rel(P_rel, g);
    phase_attn(t);
    BLOCK_FENCE();
    arrive(A_int, A_fin, A_rel, g);
    if (t > 0) phase_ev(hsrc, t - 1);       // slack window (uniform on all blocks)
    if (t < TSTEPS - 1) prefetch_issue(t + 1);
    wait_rel(A_rel, g);
    if (t < TSTEPS - 1) prefetch_commit();
    phase_gru(hsrc, hdst, t);
    BLOCK_FENCE();
    arrive(H_int, H_fin, H_rel, g);
    wait_rel(H_rel, g);
    if (t < TSTEPS - 1) {
      proj_k(hdst);
      BLOCK_FENCE();
      arrive(P_int, P_fin, P_rel, g + 1u);
    }
  }
  phase_ev(hb1, TSTEPS - 1);  // tail e,v (h_63 lives in hb1)
}

// ---- parallel c-scan: c_t = c_{t-1}*(1 - w_t e_t) + w_t v_t ----
__global__ void __launch_bounds__(256) ntm_cscan(
    const float* __restrict__ c0, const float* __restrict__ wsf,
    float* __restrict__ out)
{
  const float* wbuf = wsf + 2 * NBAT * HD + NBAT * C2D + 64 + NBAT * 4 * PSTRIDE;
  const float* earr = wbuf + NBAT * TSTEPS * C1D;
  const float* varr = earr + NBAT * TSTEPS * C2D;
  float* cs_out = out + NBAT * TSTEPS * HD;

  const int tid = threadIdx.x;
  const int lane = tid & 63, wid = tid >> 6;
  const int n = blockIdx.x >> 3, g = blockIdx.x & 7;
  const int i0 = g * 16 + wid * 4;

  f32x4 c[4];
#pragma unroll
  for (int r = 0; r < 4; ++r)
    c[r] = *(const f32x4*)(c0 + ((size_t)(n * C1D + i0 + r)) * C2D + lane * 4);

  const float* ep = earr + (size_t)n * TSTEPS * C2D + lane * 4;
  const float* vp = varr + (size_t)n * TSTEPS * C2D + lane * 4;
  const float* wp = wbuf + (size_t)n * TSTEPS * C1D + i0;

  f32x4 e_nxt = *(const f32x4*)(ep);
  f32x4 v_nxt = *(const f32x4*)(vp);
  for (int t = 0; t < TSTEPS; ++t) {
    const f32x4 e4 = e_nxt, v4 = v_nxt;
    if (t + 1 < TSTEPS) {
      e_nxt = *(const f32x4*)(ep + (t + 1) * C2D);
      v_nxt = *(const f32x4*)(vp + (t + 1) * C2D);
    }
#pragma unroll
    for (int r = 0; r < 4; ++r) {
      const float wr = wp[t * C1D + r];
      c[r] = c[r] * (1.f - wr * e4) + wr * v4;
      __builtin_nontemporal_store(
          c[r], (f32x4*)(cs_out + ((size_t)((n * TSTEPS + t) * C1D + i0 + r)) * C2D + lane * 4));
    }
  }
}

extern "C" void kernel_launch(void* const* d_in, const int* in_sizes, int n_in,
                              void* d_out, int out_size, void* d_ws, size_t ws_size,
                              hipStream_t stream) {
  const float* h0 = (const float*)d_in[0];
  const float* c0 = (const float*)d_in[1];
  const float* c_x = (const float*)d_in[2];
  const float* Wk = (const float*)d_in[3];
  const float* bk = (const float*)d_in[4];
  const float* Wb = (const float*)d_in[5];
  const float* bb = (const float*)d_in[6];
  const float* We = (const float*)d_in[7];
  const float* be = (const float*)d_in[8];
  const float* Wv = (const float*)d_in[9];
  const float* bv = (const float*)d_in[10];
  const float* Wih = (const float*)d_in[11];
  const float* bih = (const float*)d_in[12];
  const float* Whh = (const float*)d_in[13];
  const float* bhh = (const float*)d_in[14];

  unsigned* flags = (unsigned*)d_ws;
  float* wsf = (float*)((char*)d_ws + 16384);

  (void)hipMemsetAsync(d_ws, 0, 16384, stream);  // reset flags (deterministic replay)
  ntm_chain<<<dim3(NBLK), dim3(256), 0, stream>>>(h0, c_x, Wk, bk, Wb, bb, We, be, Wv, bv,
                                                  Wih, bih, Whh, bhh, (float*)d_out, wsf, flags);
  ntm_cscan<<<dim3(256), dim3(256), 0, stream>>>(c0, wsf, (float*)d_out);
}